// Round 1
// baseline (112.080 us; speedup 1.0000x reference)
//
#include <hip/hip_runtime.h>

// Denoiser: 6-layer MLP (2->16, 5x 16->16, 16->2), ReLU between, fp32.
// Compute-bound on fp32 VALU (AI ~168 FLOP/byte). Strategy:
//  - 1 point/thread, h kept as 8 float2 register pairs
//  - weights accessed at wave-uniform addresses -> s_load (scalar pipe)
//  - inner products as v2f32 FMA -> v_pk_fma_f32 (packed fp32, 2x rate)
//  - weight pairs (w[j][2k], w[j][2k+1]) contiguous -> s_load_dwordx2
//    SGPR-pair operand to the packed FMA (no broadcast movs needed)

typedef float v2f __attribute__((ext_vector_type(2)));

__global__ __launch_bounds__(256) void denoiser_mlp_kernel(
    const v2f* __restrict__ x,       // [N] of (x0,x1)
    const float* __restrict__ w_in,  // [16][2]
    const float* __restrict__ w_mid, // [5][16][16]
    const float* __restrict__ w_out, // [2][16]
    v2f* __restrict__ out,           // [N] of (o0,o1)
    int n)
{
    int i = blockIdx.x * blockDim.x + threadIdx.x;
    if (i >= n) return;

    v2f xy = x[i];

    // hidden state: 16 features as 8 aligned pairs
    v2f h2[8];

    // ---- input layer: h[j] = relu(x0*w_in[j][0] + x1*w_in[j][1]) ----
    #pragma unroll
    for (int jp = 0; jp < 8; ++jp) {
        float a0 = __builtin_fmaf(xy.y, w_in[4*jp + 1], xy.x * w_in[4*jp + 0]);
        float a1 = __builtin_fmaf(xy.y, w_in[4*jp + 3], xy.x * w_in[4*jp + 2]);
        v2f a = {a0, a1};
        h2[jp] = __builtin_elementwise_max(a, (v2f){0.f, 0.f});
    }

    // ---- 5 mid layers: h_new[j] = relu(sum_k h[k] * w_mid[l][j][k]) ----
    const v2f* wm2 = (const v2f*)w_mid;  // [5][16][8] pairs, uniform addr -> s_load
    #pragma unroll
    for (int l = 0; l < 5; ++l) {
        v2f ns[8];
        #pragma unroll
        for (int jp = 0; jp < 8; ++jp) {
            const v2f* wr0 = wm2 + (l * 16 + 2 * jp) * 8;       // row j=2*jp
            const v2f* wr1 = wm2 + (l * 16 + 2 * jp + 1) * 8;   // row j=2*jp+1
            v2f acc0 = h2[0] * wr0[0];
            v2f acc1 = h2[0] * wr1[0];
            #pragma unroll
            for (int k = 1; k < 8; ++k) {
                acc0 = __builtin_elementwise_fma(h2[k], wr0[k], acc0);
                acc1 = __builtin_elementwise_fma(h2[k], wr1[k], acc1);
            }
            v2f s = {acc0.x + acc0.y, acc1.x + acc1.y};
            ns[jp] = s;
        }
        #pragma unroll
        for (int jp = 0; jp < 8; ++jp)
            h2[jp] = __builtin_elementwise_max(ns[jp], (v2f){0.f, 0.f});
    }

    // ---- output layer: out[o] = sum_k h[k] * w_out[o][k] (no relu) ----
    const v2f* wo2 = (const v2f*)w_out;  // [2][8] pairs
    v2f acc0 = h2[0] * wo2[0];
    v2f acc1 = h2[0] * wo2[8];
    #pragma unroll
    for (int k = 1; k < 8; ++k) {
        acc0 = __builtin_elementwise_fma(h2[k], wo2[k], acc0);
        acc1 = __builtin_elementwise_fma(h2[k], wo2[8 + k], acc1);
    }
    v2f o = {acc0.x + acc0.y, acc1.x + acc1.y};
    out[i] = o;
}

extern "C" void kernel_launch(void* const* d_in, const int* in_sizes, int n_in,
                              void* d_out, int out_size, void* d_ws, size_t ws_size,
                              hipStream_t stream) {
    const float* x     = (const float*)d_in[0];
    const float* w_in  = (const float*)d_in[1];
    const float* w_mid = (const float*)d_in[2];
    const float* w_out = (const float*)d_in[3];

    int n = in_sizes[0] / 2;  // N points, 2 coords each
    int threads = 256;
    int blocks = (n + threads - 1) / threads;

    denoiser_mlp_kernel<<<blocks, threads, 0, stream>>>(
        (const v2f*)x, w_in, w_mid, w_out, (v2f*)d_out, n);
}

// Round 3
// 49.493 us; speedup vs baseline: 2.2645x; 2.2645x over previous
//
#include <hip/hip_runtime.h>

// Denoiser MLP (2->16, 5x 16->16, 16->2), fp32 in/out, via fp16 MFMA.
//
// Layout trick: keep activations TRANSPOSED g = h^T (features x points) and
// compute each layer as D = W * g with W as the A operand, g as the B operand
// of v_mfma_f32_16x16x16_f16. For this shape:
//   A frag: lane holds A[i=lane&15][k=4*(lane>>4)+j], j=0..3
//   B frag: lane holds B[k=4*(lane>>4)+j][n=lane&15]
//   D frag: lane holds D[i=4*(lane>>4)+r][n=lane&15]
// D's layout == B's layout (row index plays k) -> each layer's output feeds
// the next layer's B operand with ZERO cross-lane traffic: just relu + cvt.
// Input layer in fp32 on VALU (K=2); output layer = one MFMA with W_out
// zero-padded to 16 rows; outputs land in lanes 0-15 as contiguous float2.

typedef _Float16 h4 __attribute__((ext_vector_type(4)));
typedef _Float16 h2 __attribute__((ext_vector_type(2)));
typedef __fp16   q2 __attribute__((ext_vector_type(2)));  // cvt_pkrtz return type
typedef float f4 __attribute__((ext_vector_type(4)));
typedef float f2 __attribute__((ext_vector_type(2)));

static __device__ __forceinline__ f4 mfma16(h4 a, h4 b, f4 c) {
    return __builtin_amdgcn_mfma_f32_16x16x16f16(a, b, c, 0, 0, 0);
}

static __device__ __forceinline__ h4 relu_cvt(f4 acc, f4 zero) {
    f4 r = __builtin_elementwise_max(acc, zero);
    h2 lo = __builtin_bit_cast(h2, __builtin_amdgcn_cvt_pkrtz(r.x, r.y));
    h2 hi = __builtin_bit_cast(h2, __builtin_amdgcn_cvt_pkrtz(r.z, r.w));
    h4 hb; hb[0] = lo[0]; hb[1] = lo[1]; hb[2] = hi[0]; hb[3] = hi[1];
    return hb;
}

__global__ __launch_bounds__(256) void denoiser_mfma(
    const f2* __restrict__ x,        // [N] points (x0,x1)
    const float* __restrict__ w_in,  // [16][2]
    const float* __restrict__ w_mid, // [5][16][16]
    const float* __restrict__ w_out, // [2][16]
    f2* __restrict__ out,            // [N] (o0,o1)
    int n)
{
    const int lane = threadIdx.x & 63;
    const int m    = lane & 15;   // point-in-tile / output column
    const int g    = lane >> 4;   // k-group (4 consecutive k per group)
    const int wave = threadIdx.x >> 6;
    const int base = blockIdx.x * 256 + wave * 64;  // 4 tiles of 16 pts/wave

    const f4 zero = (f4){0.f, 0.f, 0.f, 0.f};

    // ---- one-time per-wave weight fragments ----
    // input layer: per-lane rows k=4g+j, columns of w_in
    f4 wic0, wic1;
    {
        const f4* w4 = (const f4*)w_in;   // 8x float4 over [16][2]
        f4 a = w4[2 * g], b = w4[2 * g + 1];
        wic0 = (f4){a.x, a.z, b.x, b.z};  // w_in[4g+j][0]
        wic1 = (f4){a.y, a.w, b.y, b.w};  // w_in[4g+j][1]
    }
    // mid layers: A frag = w_mid[l][i=m][k=4g+j]  (RTE converts, once)
    h4 wm[5];
    #pragma unroll
    for (int l = 0; l < 5; ++l) {
        f4 v = *(const f4*)(w_mid + l * 256 + m * 16 + 4 * g);
        h4 h; h[0] = (_Float16)v.x; h[1] = (_Float16)v.y;
              h[2] = (_Float16)v.z; h[3] = (_Float16)v.w;
        wm[l] = h;
    }
    // output layer: A frag = w_out padded to 16 rows (rows 0,1 nonzero)
    h4 wo = (h4){(_Float16)0.f, (_Float16)0.f, (_Float16)0.f, (_Float16)0.f};
    if (m < 2) {
        f4 v = *(const f4*)(w_out + m * 16 + 4 * g);
        wo[0] = (_Float16)v.x; wo[1] = (_Float16)v.y;
        wo[2] = (_Float16)v.z; wo[3] = (_Float16)v.w;
    }

    // ---- input layer (fp32 VALU), 4 tiles ----
    h4 b[4];
    int pidx[4];
    #pragma unroll
    for (int t = 0; t < 4; ++t) {
        int pi = base + t * 16 + m;
        pidx[t] = pi;
        int pc = pi < n ? pi : 0;       // clamp OOB loads
        f2 xy = x[pc];
        f4 a = wic0 * xy.x + wic1 * xy.y;   // h[m][4g+j], fp32
        b[t] = relu_cvt(a, zero);
    }

    // ---- 5 mid layers: 1 MFMA per tile per layer, no cross-lane ----
    f4 acc[4];
    #pragma unroll
    for (int l = 0; l < 5; ++l) {
        #pragma unroll
        for (int t = 0; t < 4; ++t)
            acc[t] = mfma16(wm[l], b[t], zero);
        #pragma unroll
        for (int t = 0; t < 4; ++t)
            b[t] = relu_cvt(acc[t], zero);
    }

    // ---- output layer: rows 0,1 of D land in lane-group 0, regs 0,1 ----
    #pragma unroll
    for (int t = 0; t < 4; ++t)
        acc[t] = mfma16(wo, b[t], zero);

    if (g == 0) {
        #pragma unroll
        for (int t = 0; t < 4; ++t) {
            if (pidx[t] < n)
                out[pidx[t]] = (f2){acc[t].x, acc[t].y};
        }
    }
}

extern "C" void kernel_launch(void* const* d_in, const int* in_sizes, int n_in,
                              void* d_out, int out_size, void* d_ws, size_t ws_size,
                              hipStream_t stream) {
    const float* x     = (const float*)d_in[0];
    const float* w_in  = (const float*)d_in[1];
    const float* w_mid = (const float*)d_in[2];
    const float* w_out = (const float*)d_in[3];

    int n = in_sizes[0] / 2;          // number of points
    int blocks = (n + 255) / 256;     // 256 threads = 4 waves = 256 points

    denoiser_mfma<<<blocks, 256, 0, stream>>>(
        (const f2*)x, w_in, w_mid, w_out, (f2*)d_out, n);
}

// Round 4
// 36.333 us; speedup vs baseline: 3.0848x; 1.3622x over previous
//
#include <hip/hip_runtime.h>

// Denoiser MLP (2->16, 5x 16->16, 16->2), fp32 in/out, via fp16 MFMA.
// R4: VALU-count reduction. R3 measured ~790 VALU instr/wave (VALUBusy 80%)
// vs ~250 ideal. Changes:
//  - persistent grid-stride (2048 blocks, 8 chunks each): weight-frag prep
//    amortized 8x instead of paid per 256 points
//  - h4 built by bit_cast of a u32x2 (no half-register element inserts)
//  - ReLU as v_pk_max_f16 after cvt_pkrtz (2 instr) instead of 4x v_max_f32
//  - weight f32->f16 via cvt_pkrtz (2 instr/frag vs 4 cvt + packing)
//  - bounds checks: single uniform branch per 64-pt wave-chunk; full path
//    (always taken at N=4194304) has zero per-tile compares
//
// MFMA layout (16x16x16 f16, D=W*g with activations transposed):
//   A frag: lane holds A[i=lane&15][k=4*(lane>>4)+j]
//   B frag: lane holds B[k=4*(lane>>4)+j][n=lane&15]
//   D frag: lane holds D[i=4*(lane>>4)+r][n=lane&15]
// D layout == B layout -> layer chaining with zero cross-lane traffic.

typedef _Float16 h4 __attribute__((ext_vector_type(4)));
typedef _Float16 h2 __attribute__((ext_vector_type(2)));
typedef float f4 __attribute__((ext_vector_type(4)));
typedef float f2 __attribute__((ext_vector_type(2)));
typedef unsigned int u32;
typedef u32 u2v __attribute__((ext_vector_type(2)));

static __device__ __forceinline__ f4 mfma16(h4 a, h4 b, f4 c) {
    return __builtin_amdgcn_mfma_f32_16x16x16f16(a, b, c, 0, 0, 0);
}

static __device__ __forceinline__ h4 pack2(h2 l, h2 h) {
    u2v p = { __builtin_bit_cast(u32, l), __builtin_bit_cast(u32, h) };
    return __builtin_bit_cast(h4, p);
}

static __device__ __forceinline__ h4 cvt4(f4 v) {
    h2 lo = __builtin_bit_cast(h2, __builtin_amdgcn_cvt_pkrtz(v.x, v.y));
    h2 hi = __builtin_bit_cast(h2, __builtin_amdgcn_cvt_pkrtz(v.z, v.w));
    return pack2(lo, hi);
}

static __device__ __forceinline__ h4 cvt_relu(f4 v) {
    h2 lo = __builtin_bit_cast(h2, __builtin_amdgcn_cvt_pkrtz(v.x, v.y));
    h2 hi = __builtin_bit_cast(h2, __builtin_amdgcn_cvt_pkrtz(v.z, v.w));
    const h2 z = {(_Float16)0.f, (_Float16)0.f};
    lo = __builtin_elementwise_max(lo, z);   // v_pk_max_f16
    hi = __builtin_elementwise_max(hi, z);
    return pack2(lo, hi);
}

__global__ __launch_bounds__(256) void denoiser_mfma(
    const f2* __restrict__ x,        // [N] points (x0,x1)
    const float* __restrict__ w_in,  // [16][2]
    const float* __restrict__ w_mid, // [5][16][16]
    const float* __restrict__ w_out, // [2][16]
    f2* __restrict__ out,            // [N] (o0,o1)
    int n)
{
    const int lane = threadIdx.x & 63;
    const int m    = lane & 15;   // point-in-tile / A-row index
    const int g    = lane >> 4;   // k-group
    const int wave = threadIdx.x >> 6;

    const f4 zero = (f4){0.f, 0.f, 0.f, 0.f};

    // ---- one-time weight fragments (amortized over all chunks) ----
    f4 wic0, wic1;
    {
        const f4* w4 = (const f4*)w_in;   // 8x float4 over [16][2]
        f4 a = w4[2 * g], b = w4[2 * g + 1];
        wic0 = (f4){a.x, a.z, b.x, b.z};  // w_in[4g+j][0]
        wic1 = (f4){a.y, a.w, b.y, b.w};  // w_in[4g+j][1]
    }
    h4 wm[5];
    #pragma unroll
    for (int l = 0; l < 5; ++l)
        wm[l] = cvt4(*(const f4*)(w_mid + l * 256 + m * 16 + 4 * g));
    h4 wo = (h4){(_Float16)0.f, (_Float16)0.f, (_Float16)0.f, (_Float16)0.f};
    if (m < 2)
        wo = cvt4(*(const f4*)(w_out + m * 16 + 4 * g));

    const int nchunks = (n + 255) >> 8;     // 256 points per block-chunk

    for (int c = blockIdx.x; c < nchunks; c += gridDim.x) {
        const int base = c * 256 + wave * 64;   // this wave's 64 points
        const bool full = (base + 64 <= n);     // wave-uniform

        // ---- load x, input layer (fp32 VALU), 4 tiles of 16 points ----
        f2 xy[4];
        if (full) {
            #pragma unroll
            for (int t = 0; t < 4; ++t)
                xy[t] = x[base + t * 16 + m];
        } else {
            #pragma unroll
            for (int t = 0; t < 4; ++t) {
                int pi = base + t * 16 + m;
                xy[t] = pi < n ? x[pi] : (f2){0.f, 0.f};
            }
        }

        h4 b[4];
        #pragma unroll
        for (int t = 0; t < 4; ++t)
            b[t] = cvt_relu(wic0 * xy[t].x + wic1 * xy[t].y);

        // ---- 5 mid layers: 1 MFMA + 1 cvt_relu per tile per layer ----
        #pragma unroll
        for (int l = 0; l < 5; ++l) {
            f4 acc[4];
            #pragma unroll
            for (int t = 0; t < 4; ++t)
                acc[t] = mfma16(wm[l], b[t], zero);
            #pragma unroll
            for (int t = 0; t < 4; ++t)
                b[t] = cvt_relu(acc[t]);
        }

        // ---- output layer ----
        f4 acc[4];
        #pragma unroll
        for (int t = 0; t < 4; ++t)
            acc[t] = mfma16(wo, b[t], zero);

        if (g == 0) {
            if (full) {
                #pragma unroll
                for (int t = 0; t < 4; ++t)
                    out[base + t * 16 + m] = (f2){acc[t].x, acc[t].y};
            } else {
                #pragma unroll
                for (int t = 0; t < 4; ++t) {
                    int pi = base + t * 16 + m;
                    if (pi < n) out[pi] = (f2){acc[t].x, acc[t].y};
                }
            }
        }
    }
}

extern "C" void kernel_launch(void* const* d_in, const int* in_sizes, int n_in,
                              void* d_out, int out_size, void* d_ws, size_t ws_size,
                              hipStream_t stream) {
    const float* x     = (const float*)d_in[0];
    const float* w_in  = (const float*)d_in[1];
    const float* w_mid = (const float*)d_in[2];
    const float* w_out = (const float*)d_in[3];

    int n = in_sizes[0] / 2;          // number of points
    int nchunks = (n + 255) / 256;
    int blocks = nchunks < 2048 ? nchunks : 2048;  // 8 blocks/CU persistent

    denoiser_mfma<<<blocks, 256, 0, stream>>>(
        (const f2*)x, w_in, w_mid, w_out, (f2*)d_out, n);
}